// Round 2
// baseline (232.389 us; speedup 1.0000x reference)
//
#include <hip/hip_runtime.h>
#include <hip/hip_bf16.h>

typedef unsigned short u16;
typedef unsigned int u32;
typedef __attribute__((ext_vector_type(8))) short short8v;
typedef __attribute__((ext_vector_type(4))) float f32x4;

#define M_ROWS 2048
#define N_COLS 10572
#define K_DIM 512
#define N_PAD 10624
#define SCALE_F 30.0f
#define PI_F 3.14159265358979f

__device__ __forceinline__ u16 bf16rne(float f) {
    u32 u = __float_as_uint(f);
    u += 0x7FFFu + ((u >> 16) & 1u);
    return (u16)(u >> 16);
}

// ---------------- normalize rows, emit bf16 (pad rows -> zeros) ----------------
__global__ void k_normalize(const float* __restrict__ src, int realRows,
                            u16* __restrict__ dst, float* __restrict__ norms) {
    const int row = blockIdx.x;
    const int lane = threadIdx.x;  // 64
    if (row >= realRows) {
        ((uint4*)dst)[(size_t)row * 64 + lane] = make_uint4(0, 0, 0, 0);
        return;
    }
    const float4* p = (const float4*)src + (size_t)row * 128 + lane * 2;
    float4 a = p[0], b = p[1];
    float ss = a.x*a.x + a.y*a.y + a.z*a.z + a.w*a.w
             + b.x*b.x + b.y*b.y + b.z*b.z + b.w*b.w;
    for (int d = 32; d; d >>= 1) ss += __shfl_xor(ss, d, 64);
    const float nrm = sqrtf(ss);
    const float inv = 1.0f / nrm;
    if (lane == 0) norms[row] = nrm;
    uint4 v;
    v.x = (u32)bf16rne(a.x*inv) | ((u32)bf16rne(a.y*inv) << 16);
    v.y = (u32)bf16rne(a.z*inv) | ((u32)bf16rne(a.w*inv) << 16);
    v.z = (u32)bf16rne(b.x*inv) | ((u32)bf16rne(b.y*inv) << 16);
    v.w = (u32)bf16rne(b.z*inv) | ((u32)bf16rne(b.w*inv) << 16);
    ((uint4*)dst)[(size_t)row * 64 + lane] = v;
}

// ---------------- precise f32 gt dot ----------------
__global__ void k_gt_dot(const float* __restrict__ feat, const float* __restrict__ wgt,
                         const int* __restrict__ label, const float* __restrict__ fnorm,
                         const float* __restrict__ wnorm, float* __restrict__ cosgt) {
    const int i = blockIdx.x, lane = threadIdx.x;  // 64
    const int lab = label[i];
    const float4* pf = (const float4*)feat + (size_t)i * 128 + lane * 2;
    const float4* pw = (const float4*)wgt + (size_t)lab * 128 + lane * 2;
    float4 a = pf[0], b = pf[1], c = pw[0], d = pw[1];
    float s = a.x*c.x + a.y*c.y + a.z*c.z + a.w*c.w
            + b.x*d.x + b.y*d.y + b.z*d.z + b.w*d.w;
    for (int dd = 32; dd; dd >>= 1) s += __shfl_xor(s, dd, 64);
    if (lane == 0) cosgt[i] = s / (fnorm[i] * wnorm[lab]);
}

// ---------------- theta stats + per-row marginal gt logit value ----------------
__global__ void k_stats(const float* __restrict__ cosgt, float* __restrict__ gtml) {
    const int t = threadIdx.x;           // 1024
    const int lane = t & 63, w = t >> 6; // 16 waves
    __shared__ float smax[16], smin[16];
    __shared__ double ssum[16];
    __shared__ float bcast[3];
    float c0 = fminf(fmaxf(cosgt[t], -1.f), 1.f);
    float c1 = fminf(fmaxf(cosgt[t + 1024], -1.f), 1.f);
    float th0 = acosf(c0) * (180.f / PI_F);
    float th1 = acosf(c1) * (180.f / PI_F);
    float mx = fmaxf(th0, th1), mn = fminf(th0, th1);
    double sm = (double)th0 + (double)th1;
    for (int d = 32; d; d >>= 1) {
        mx = fmaxf(mx, __shfl_xor(mx, d, 64));
        mn = fminf(mn, __shfl_xor(mn, d, 64));
        sm += __shfl_xor(sm, d, 64);
    }
    if (lane == 0) { smax[w] = mx; smin[w] = mn; ssum[w] = sm; }
    __syncthreads();
    if (t == 0) {
        float MX = smax[0], MN = smin[0]; double SM = ssum[0];
        for (int j = 1; j < 16; ++j) {
            MX = fmaxf(MX, smax[j]); MN = fminf(MN, smin[j]); SM += ssum[j];
        }
        float avg = (float)(SM / 2048.0);
        float mhi = (MX < 90.f) ? (90.f - avg) * (PI_F / 180.f) : 0.f;
        float mlo = MN * (PI_F / 180.f);
        bcast[0] = avg; bcast[1] = mhi; bcast[2] = mlo;
    }
    __syncthreads();
    const float avg = bcast[0], mhi = bcast[1], mlo = bcast[2];
    #pragma unroll
    for (int k = 0; k < 2; ++k) {
        const int r = t + k * 1024;
        const float th = k ? th1 : th0;
        const float cg = k ? c1 : c0;
        const float m = (th > avg) ? mhi : mlo;
        const bool inside = cg > -cosf(m);
        const float add = inside ? m : 0.f;
        const float ext = inside ? 0.f : (-m * sinf(m));
        gtml[r] = SCALE_F * (cosf(acosf(cg) + add) + ext);
    }
}

// ---------------- main bf16 MFMA GEMM: direct register loads, no LDS, no barriers ----------------
// 128x128 tile, 4 waves (2x2), fragments gathered straight from global (L2-resident).
// Each frag load: 64 lanes x 16B = 16 full 64B cache lines (kg covers a 64B row segment).
__global__ void __launch_bounds__(256, 3)
k_gemm(const u16* __restrict__ nfb, const u16* __restrict__ nwb,
       const int* __restrict__ label, const float* __restrict__ gtml,
       float* __restrict__ cosO, float* __restrict__ mlO,
       float* __restrict__ rowsum, float* __restrict__ cosLast) {
    const int tid = threadIdx.x;
    const int lane = tid & 63;
    const int wid = tid >> 6;          // 0..3
    const int wm = wid >> 1, wn = wid & 1;
    const int tm = blockIdx.y * 128;
    const int tn = blockIdx.x * 128;
    const int kg = lane >> 4, lr = lane & 15;

    // per-lane base addresses (kt folds into the 13-bit imm offset: kt*64B <= 960)
    const u16* aBase = nfb + ((size_t)(tm + wm * 64 + lr) * K_DIM + kg * 8);
    const u16* bBase = nwb + ((size_t)(tn + wn * 64 + lr) * K_DIM + kg * 8);

    f32x4 acc[4][4] = {};
    #pragma unroll
    for (int kt = 0; kt < 16; ++kt) {
        short8v af[4], bfv[4];
        #pragma unroll
        for (int mf = 0; mf < 4; ++mf)
            af[mf] = *(const short8v*)(aBase + (size_t)mf * 16 * K_DIM + kt * 32);
        #pragma unroll
        for (int nf = 0; nf < 4; ++nf)
            bfv[nf] = *(const short8v*)(bBase + (size_t)nf * 16 * K_DIM + kt * 32);
        #pragma unroll
        for (int mf = 0; mf < 4; ++mf)
            #pragma unroll
            for (int nf = 0; nf < 4; ++nf)
                acc[mf][nf] = __builtin_amdgcn_mfma_f32_16x16x32_bf16(
                    af[mf], bfv[nf], acc[mf][nf], 0, 0, 0);
    }

    // epilogue: cos, marginal logits (gt entries patched inline), exp row-sums, cos[:,label_last]
    const int labL = label[M_ROWS - 1];
    #pragma unroll
    for (int mf = 0; mf < 4; ++mf) {
        #pragma unroll
        for (int r = 0; r < 4; ++r) {
            const int row = tm + wm * 64 + mf * 16 + kg * 4 + r;
            const int lab = label[row];
            const float gml = gtml[row];
            float rs = 0.f;
            #pragma unroll
            for (int nf = 0; nf < 4; ++nf) {
                const int col = tn + wn * 64 + nf * 16 + lr;
                const float v = acc[mf][nf][r];
                if (col < N_COLS) {
                    const size_t idx = (size_t)row * N_COLS + col;
                    __builtin_nontemporal_store(v, &cosO[idx]);
                    const float ml = (col == lab) ? gml : SCALE_F * v;
                    __builtin_nontemporal_store(ml, &mlO[idx]);
                    rs += __expf(SCALE_F * v);
                    if (col == labL) cosLast[row] = v;
                }
            }
            #pragma unroll
            for (int d = 1; d < 16; d <<= 1) rs += __shfl_xor(rs, d, 64);
            if (lr == 0) atomicAdd(&rowsum[row], rs);
        }
    }
}

// ---------------- final scalar stats ----------------
__global__ void k_final(const float* __restrict__ rowsum, const float* __restrict__ cosLast,
                        float* __restrict__ outS) {
    const int t = threadIdx.x;           // 1024
    const int lane = t & 63, w = t >> 6;
    __shared__ float smin[16], smax[16];
    __shared__ double ssum[16], sbs[16];
    double psum = 0.0, bsum = 0.0;
    float mn = 1e30f, mx = -1e30f;
    #pragma unroll
    for (int k = 0; k < 2; ++k) {
        const int r = t + k * 1024;
        const float e = expf(SCALE_F * cosLast[r]);
        const float rsv = rowsum[r];
        const float p = e / rsv;
        psum += (double)p;
        bsum += (double)rsv - (double)e;
        mn = fminf(mn, p); mx = fmaxf(mx, p);
    }
    for (int d = 32; d; d >>= 1) {
        mn = fminf(mn, __shfl_xor(mn, d, 64));
        mx = fmaxf(mx, __shfl_xor(mx, d, 64));
        psum += __shfl_xor(psum, d, 64);
        bsum += __shfl_xor(bsum, d, 64);
    }
    if (lane == 0) { smin[w] = mn; smax[w] = mx; ssum[w] = psum; sbs[w] = bsum; }
    __syncthreads();
    if (t == 0) {
        float MN = smin[0], MX = smax[0]; double PS = ssum[0], BS = sbs[0];
        for (int j = 1; j < 16; ++j) {
            MN = fminf(MN, smin[j]); MX = fmaxf(MX, smax[j]);
            PS += ssum[j]; BS += sbs[j];
        }
        outS[0] = (float)(PS / 2048.0);                 // avg_p
        outS[1] = MN;                                   // min_p
        outS[2] = MX;                                   // max_p
        const double mb = BS / 2048.0 / (double)(N_COLS - 1);
        outS[3] = (float)(acos(log(mb) / 30.0) * (180.0 / 3.14159265358979));  // B_avg
    }
}

extern "C" void kernel_launch(void* const* d_in, const int* in_sizes, int n_in,
                              void* d_out, int out_size, void* d_ws, size_t ws_size,
                              hipStream_t stream) {
    const float* feat = (const float*)d_in[0];
    const int* label = (const int*)d_in[1];
    const float* weights = (const float*)d_in[2];

    char* ws = (char*)d_ws;
    u16* nfb      = (u16*)(ws);                       // 2048*512*2      = 2,097,152
    u16* nwb      = (u16*)(ws + 2097152);             // 10624*512*2    = 10,878,976
    float* fnorm  = (float*)(ws + 12976128);          // 2048*4
    float* wnorm  = (float*)(ws + 12984320);          // 10572*4
    float* cosgt  = (float*)(ws + 13026608);          // 2048*4
    float* gtml   = (float*)(ws + 13034800);          // 2048*4
    float* rowsum = (float*)(ws + 13042992);          // 2048*4
    float* cosLast= (float*)(ws + 13051184);          // 2048*4

    float* cosO = (float*)d_out;
    float* mlO  = cosO + (size_t)M_ROWS * N_COLS;
    float* outS = cosO + (size_t)2 * M_ROWS * N_COLS;

    hipMemsetAsync(rowsum, 0, M_ROWS * sizeof(float), stream);

    k_normalize<<<M_ROWS, 64, 0, stream>>>(feat, M_ROWS, nfb, fnorm);
    k_normalize<<<N_PAD, 64, 0, stream>>>(weights, N_COLS, nwb, wnorm);
    k_gt_dot<<<M_ROWS, 64, 0, stream>>>(feat, weights, label, fnorm, wnorm, cosgt);
    k_stats<<<1, 1024, 0, stream>>>(cosgt, gtml);

    dim3 grid(83, 16);  // ceil(10572/128) x 2048/128
    k_gemm<<<grid, 256, 0, stream>>>(nfb, nwb, label, gtml, cosO, mlO, rowsum, cosLast);

    k_final<<<1, 1024, 0, stream>>>(rowsum, cosLast, outS);
}

// Round 3
// 130.319 us; speedup vs baseline: 1.7832x; 1.7832x over previous
//
#include <hip/hip_runtime.h>
#include <hip/hip_bf16.h>

typedef unsigned short u16;
typedef unsigned int u32;
typedef __attribute__((ext_vector_type(8))) short short8v;
typedef __attribute__((ext_vector_type(4))) float f32x4;

#define M_ROWS 2048
#define N_COLS 10572
#define K_DIM 512
#define N_PAD 10624
#define SCALE_F 30.0f
#define PI_F 3.14159265358979f
#define NBX 83          // ceil(10572/128)
#define NBY 16          // 2048/128
#define NWG (NBX*NBY)   // 1328 = 8 * 166
#define NSLOT (NBX*2)   // partial-sum slots

__device__ __forceinline__ u16 bf16rne(float f) {
    u32 u = __float_as_uint(f);
    u += 0x7FFFu + ((u >> 16) & 1u);
    return (u16)(u >> 16);
}

// ---------------- normalize rows, emit bf16 (pad rows -> zeros) ----------------
__global__ void k_normalize(const float* __restrict__ src, int realRows,
                            u16* __restrict__ dst, float* __restrict__ norms) {
    const int row = blockIdx.x;
    const int lane = threadIdx.x;  // 64
    if (row >= realRows) {
        ((uint4*)dst)[(size_t)row * 64 + lane] = make_uint4(0, 0, 0, 0);
        return;
    }
    const float4* p = (const float4*)src + (size_t)row * 128 + lane * 2;
    float4 a = p[0], b = p[1];
    float ss = a.x*a.x + a.y*a.y + a.z*a.z + a.w*a.w
             + b.x*b.x + b.y*b.y + b.z*b.z + b.w*b.w;
    for (int d = 32; d; d >>= 1) ss += __shfl_xor(ss, d, 64);
    const float nrm = sqrtf(ss);
    const float inv = 1.0f / nrm;
    if (lane == 0) norms[row] = nrm;
    uint4 v;
    v.x = (u32)bf16rne(a.x*inv) | ((u32)bf16rne(a.y*inv) << 16);
    v.y = (u32)bf16rne(a.z*inv) | ((u32)bf16rne(a.w*inv) << 16);
    v.z = (u32)bf16rne(b.x*inv) | ((u32)bf16rne(b.y*inv) << 16);
    v.w = (u32)bf16rne(b.z*inv) | ((u32)bf16rne(b.w*inv) << 16);
    ((uint4*)dst)[(size_t)row * 64 + lane] = v;
}

// ---------------- precise f32 gt dot ----------------
__global__ void k_gt_dot(const float* __restrict__ feat, const float* __restrict__ wgt,
                         const int* __restrict__ label, const float* __restrict__ fnorm,
                         const float* __restrict__ wnorm, float* __restrict__ cosgt) {
    const int i = blockIdx.x, lane = threadIdx.x;  // 64
    const int lab = label[i];
    const float4* pf = (const float4*)feat + (size_t)i * 128 + lane * 2;
    const float4* pw = (const float4*)wgt + (size_t)lab * 128 + lane * 2;
    float4 a = pf[0], b = pf[1], c = pw[0], d = pw[1];
    float s = a.x*c.x + a.y*c.y + a.z*c.z + a.w*c.w
            + b.x*d.x + b.y*d.y + b.z*d.z + b.w*d.w;
    for (int dd = 32; dd; dd >>= 1) s += __shfl_xor(s, dd, 64);
    if (lane == 0) cosgt[i] = s / (fnorm[i] * wnorm[lab]);
}

// ---------------- theta stats + per-row marginal gt logit value ----------------
__global__ void k_stats(const float* __restrict__ cosgt, float* __restrict__ gtml) {
    const int t = threadIdx.x;           // 1024
    const int lane = t & 63, w = t >> 6; // 16 waves
    __shared__ float smax[16], smin[16];
    __shared__ double ssum[16];
    __shared__ float bcast[3];
    float c0 = fminf(fmaxf(cosgt[t], -1.f), 1.f);
    float c1 = fminf(fmaxf(cosgt[t + 1024], -1.f), 1.f);
    float th0 = acosf(c0) * (180.f / PI_F);
    float th1 = acosf(c1) * (180.f / PI_F);
    float mx = fmaxf(th0, th1), mn = fminf(th0, th1);
    double sm = (double)th0 + (double)th1;
    for (int d = 32; d; d >>= 1) {
        mx = fmaxf(mx, __shfl_xor(mx, d, 64));
        mn = fminf(mn, __shfl_xor(mn, d, 64));
        sm += __shfl_xor(sm, d, 64);
    }
    if (lane == 0) { smax[w] = mx; smin[w] = mn; ssum[w] = sm; }
    __syncthreads();
    if (t == 0) {
        float MX = smax[0], MN = smin[0]; double SM = ssum[0];
        for (int j = 1; j < 16; ++j) {
            MX = fmaxf(MX, smax[j]); MN = fminf(MN, smin[j]); SM += ssum[j];
        }
        float avg = (float)(SM / 2048.0);
        float mhi = (MX < 90.f) ? (90.f - avg) * (PI_F / 180.f) : 0.f;
        float mlo = MN * (PI_F / 180.f);
        bcast[0] = avg; bcast[1] = mhi; bcast[2] = mlo;
    }
    __syncthreads();
    const float avg = bcast[0], mhi = bcast[1], mlo = bcast[2];
    #pragma unroll
    for (int k = 0; k < 2; ++k) {
        const int r = t + k * 1024;
        const float th = k ? th1 : th0;
        const float cg = k ? c1 : c0;
        const float m = (th > avg) ? mhi : mlo;
        const bool inside = cg > -cosf(m);
        const float add = inside ? m : 0.f;
        const float ext = inside ? 0.f : (-m * sinf(m));
        gtml[r] = SCALE_F * (cosf(acosf(cg) + add) + ext);
    }
}

// ---------------- main bf16 MFMA GEMM with fused epilogue (no atomics) ----------------
// 128x128 tile, BK=32, 4 waves (2x2), double-buffered LDS, global_load_lds staging.
// Bijective XCD swizzle: consecutive blocks on one XCD share the B-tile (L2 reuse).
__global__ void __launch_bounds__(256)
k_gemm(const u16* __restrict__ nfb, const u16* __restrict__ nwb,
       const int* __restrict__ label, const float* __restrict__ gtml,
       float* __restrict__ cosO, float* __restrict__ mlO,
       float* __restrict__ partial, float* __restrict__ cosLast) {
    __shared__ __align__(16) u16 lsA[2][4096];  // 8KB per buffer
    __shared__ __align__(16) u16 lsB[2][4096];
    const int tid = threadIdx.x;
    const int lane = tid & 63;
    const int wid = tid >> 6;          // 0..3
    const int wm = wid >> 1, wn = wid & 1;

    // XCD swizzle: nwg = 1328 = 8*166 exactly -> wg = xcd*166 + lin/8 (bijective).
    // Within an XCD, consecutive wg share bx (B-tile stays in that XCD's L2).
    const int lin = blockIdx.x;
    const int wg = (lin & 7) * (NWG / 8) + (lin >> 3);
    const int bx = wg >> 4;            // 0..82  (N tile)
    const int by = wg & 15;            // 0..15  (M tile)
    const int tm = by * 128;
    const int tn = bx * 128;

    f32x4 acc[4][4] = {};

    auto stage = [&](int buf, int kt) {
        #pragma unroll
        for (int c = 0; c < 2; ++c) {
            const int s = wid * 128 + c * 64 + lane;   // slot 0..511
            const int kg2 = s >> 7, row = s & 127;
            const u16* gA = nfb + ((size_t)(tm + row) * K_DIM + kt * 32 + kg2 * 8);
            const u16* gB = nwb + ((size_t)(tn + row) * K_DIM + kt * 32 + kg2 * 8);
            u16* lA = &lsA[buf][(wid * 128 + c * 64) * 8];
            u16* lB = &lsB[buf][(wid * 128 + c * 64) * 8];
            __builtin_amdgcn_global_load_lds(
                (const __attribute__((address_space(1))) void*)gA,
                (__attribute__((address_space(3))) void*)lA, 16, 0, 0);
            __builtin_amdgcn_global_load_lds(
                (const __attribute__((address_space(1))) void*)gB,
                (__attribute__((address_space(3))) void*)lB, 16, 0, 0);
        }
    };

    stage(0, 0);
    __syncthreads();
    const int kg = lane >> 4, lr = lane & 15;
    for (int kt = 0; kt < 16; ++kt) {
        const int cur = kt & 1;
        if (kt < 15) stage(cur ^ 1, kt + 1);
        short8v af[4], bfv[4];
        #pragma unroll
        for (int mf = 0; mf < 4; ++mf)
            af[mf] = *(const short8v*)&lsA[cur][(kg * 128 + wm * 64 + mf * 16 + lr) * 8];
        #pragma unroll
        for (int nf = 0; nf < 4; ++nf)
            bfv[nf] = *(const short8v*)&lsB[cur][(kg * 128 + wn * 64 + nf * 16 + lr) * 8];
        #pragma unroll
        for (int mf = 0; mf < 4; ++mf)
            #pragma unroll
            for (int nf = 0; nf < 4; ++nf)
                acc[mf][nf] = __builtin_amdgcn_mfma_f32_16x16x32_bf16(
                    af[mf], bfv[nf], acc[mf][nf], 0, 0, 0);
        __syncthreads();
    }

    // epilogue: cos, marginal logits (gt patched inline), exp partial row-sums, cos[:,label_last]
    const int labL = label[M_ROWS - 1];
    float* prow = partial + (size_t)(bx * 2 + wn) * M_ROWS;
    #pragma unroll
    for (int mf = 0; mf < 4; ++mf) {
        #pragma unroll
        for (int r = 0; r < 4; ++r) {
            const int row = tm + wm * 64 + mf * 16 + kg * 4 + r;
            const int lab = label[row];
            const float gml = gtml[row];
            float rs = 0.f;
            #pragma unroll
            for (int nf = 0; nf < 4; ++nf) {
                const int col = tn + wn * 64 + nf * 16 + lr;
                const float v = acc[mf][nf][r];
                if (col < N_COLS) {
                    const size_t idx = (size_t)row * N_COLS + col;
                    cosO[idx] = v;
                    mlO[idx] = (col == lab) ? gml : SCALE_F * v;
                    rs += __expf(SCALE_F * v);
                    if (col == labL) cosLast[row] = v;
                }
            }
            #pragma unroll
            for (int d = 1; d < 16; d <<= 1) rs += __shfl_xor(rs, d, 64);
            if (lr == 0) prow[row] = rs;
        }
    }
}

// ---------------- reduce partial row sums: rowsum[row] = sum_j partial[j][row] ----------------
__global__ void k_rowsum(const float* __restrict__ partial, float* __restrict__ rowsum) {
    const int row = blockIdx.x * 256 + threadIdx.x;  // 8 blocks x 256
    float s = 0.f;
    for (int j = 0; j < NSLOT; ++j) s += partial[(size_t)j * M_ROWS + row];
    rowsum[row] = s;
}

// ---------------- final scalar stats ----------------
__global__ void k_final(const float* __restrict__ rowsum, const float* __restrict__ cosLast,
                        float* __restrict__ outS) {
    const int t = threadIdx.x;           // 1024
    const int lane = t & 63, w = t >> 6;
    __shared__ float smin[16], smax[16];
    __shared__ double ssum[16], sbs[16];
    double psum = 0.0, bsum = 0.0;
    float mn = 1e30f, mx = -1e30f;
    #pragma unroll
    for (int k = 0; k < 2; ++k) {
        const int r = t + k * 1024;
        const float e = expf(SCALE_F * cosLast[r]);
        const float rsv = rowsum[r];
        const float p = e / rsv;
        psum += (double)p;
        bsum += (double)rsv - (double)e;
        mn = fminf(mn, p); mx = fmaxf(mx, p);
    }
    for (int d = 32; d; d >>= 1) {
        mn = fminf(mn, __shfl_xor(mn, d, 64));
        mx = fmaxf(mx, __shfl_xor(mx, d, 64));
        psum += __shfl_xor(psum, d, 64);
        bsum += __shfl_xor(bsum, d, 64);
    }
    if (lane == 0) { smin[w] = mn; smax[w] = mx; ssum[w] = psum; sbs[w] = bsum; }
    __syncthreads();
    if (t == 0) {
        float MN = smin[0], MX = smax[0]; double PS = ssum[0], BS = sbs[0];
        for (int j = 1; j < 16; ++j) {
            MN = fminf(MN, smin[j]); MX = fmaxf(MX, smax[j]);
            PS += ssum[j]; BS += sbs[j];
        }
        outS[0] = (float)(PS / 2048.0);                 // avg_p
        outS[1] = MN;                                   // min_p
        outS[2] = MX;                                   // max_p
        const double mb = BS / 2048.0 / (double)(N_COLS - 1);
        outS[3] = (float)(acos(log(mb) / 30.0) * (180.0 / 3.14159265358979));  // B_avg
    }
}

extern "C" void kernel_launch(void* const* d_in, const int* in_sizes, int n_in,
                              void* d_out, int out_size, void* d_ws, size_t ws_size,
                              hipStream_t stream) {
    const float* feat = (const float*)d_in[0];
    const int* label = (const int*)d_in[1];
    const float* weights = (const float*)d_in[2];

    char* ws = (char*)d_ws;
    u16* nfb      = (u16*)(ws);                       // 2048*512*2     = 2,097,152
    u16* nwb      = (u16*)(ws + 2097152);             // 10624*512*2    = 10,878,976
    float* fnorm  = (float*)(ws + 12976128);          // 2048*4
    float* wnorm  = (float*)(ws + 12984320);          // 10572*4
    float* cosgt  = (float*)(ws + 13026608);          // 2048*4
    float* gtml   = (float*)(ws + 13034800);          // 2048*4
    float* rowsum = (float*)(ws + 13042992);          // 2048*4
    float* cosLast= (float*)(ws + 13051184);          // 2048*4
    float* partial= (float*)(ws + 13059376);          // 166*2048*4 = 1,359,872

    float* cosO = (float*)d_out;
    float* mlO  = cosO + (size_t)M_ROWS * N_COLS;
    float* outS = cosO + (size_t)2 * M_ROWS * N_COLS;

    k_normalize<<<M_ROWS, 64, 0, stream>>>(feat, M_ROWS, nfb, fnorm);
    k_normalize<<<N_PAD, 64, 0, stream>>>(weights, N_COLS, nwb, wnorm);
    k_gt_dot<<<M_ROWS, 64, 0, stream>>>(feat, weights, label, fnorm, wnorm, cosgt);
    k_stats<<<1, 1024, 0, stream>>>(cosgt, gtml);

    k_gemm<<<NWG, 256, 0, stream>>>(nfb, nwb, label, gtml, cosO, mlO, partial, cosLast);

    k_rowsum<<<8, 256, 0, stream>>>(partial, rowsum);
    k_final<<<1, 1024, 0, stream>>>(rowsum, cosLast, outS);
}

// Round 4
// 125.266 us; speedup vs baseline: 1.8552x; 1.0403x over previous
//
#include <hip/hip_runtime.h>
#include <hip/hip_bf16.h>

typedef unsigned short u16;
typedef unsigned int u32;
typedef __attribute__((ext_vector_type(8))) short short8v;
typedef __attribute__((ext_vector_type(4))) float f32x4;

#define M_ROWS 2048
#define N_COLS 10572
#define K_DIM 512
#define N_PAD 10624
#define SCALE_F 30.0f
#define PI_F 3.14159265358979f
#define NBX 83           // ceil(10572/128)
#define NBY 16           // 2048/128
#define NWG (NBX*NBY)    // 1328 = 8 * 166
#define NSLOT (NBX*4)    // partial-sum slots (4 N-waves per block)

__device__ __forceinline__ u16 bf16rne(float f) {
    u32 u = __float_as_uint(f);
    u += 0x7FFFu + ((u >> 16) & 1u);
    return (u16)(u >> 16);
}

// ---------------- normalize rows of feat AND weights in one launch ----------------
__global__ void k_normalize2(const float* __restrict__ feat, const float* __restrict__ wgt,
                             u16* __restrict__ nfb, u16* __restrict__ nwb,
                             float* __restrict__ fnorm, float* __restrict__ wnorm) {
    const int b = blockIdx.x;
    const int lane = threadIdx.x;  // 64
    const float* src; u16* dst; float* norms; int row; int real;
    if (b < M_ROWS) { row = b; src = feat; dst = nfb; norms = fnorm; real = 1; }
    else { row = b - M_ROWS; src = wgt; dst = nwb; norms = wnorm; real = (row < N_COLS); }
    if (!real) {
        ((uint4*)dst)[(size_t)row * 64 + lane] = make_uint4(0, 0, 0, 0);
        return;
    }
    const float4* p = (const float4*)src + (size_t)row * 128 + lane * 2;
    float4 a = p[0], bb = p[1];
    float ss = a.x*a.x + a.y*a.y + a.z*a.z + a.w*a.w
             + bb.x*bb.x + bb.y*bb.y + bb.z*bb.z + bb.w*bb.w;
    for (int d = 32; d; d >>= 1) ss += __shfl_xor(ss, d, 64);
    const float nrm = sqrtf(ss);
    const float inv = 1.0f / nrm;
    if (lane == 0) norms[row] = nrm;
    uint4 v;
    v.x = (u32)bf16rne(a.x*inv)  | ((u32)bf16rne(a.y*inv) << 16);
    v.y = (u32)bf16rne(a.z*inv)  | ((u32)bf16rne(a.w*inv) << 16);
    v.z = (u32)bf16rne(bb.x*inv) | ((u32)bf16rne(bb.y*inv) << 16);
    v.w = (u32)bf16rne(bb.z*inv) | ((u32)bf16rne(bb.w*inv) << 16);
    ((uint4*)dst)[(size_t)row * 64 + lane] = v;
}

// ---------------- precise f32 gt dot ----------------
__global__ void k_gt_dot(const float* __restrict__ feat, const float* __restrict__ wgt,
                         const int* __restrict__ label, const float* __restrict__ fnorm,
                         const float* __restrict__ wnorm, float* __restrict__ cosgt) {
    const int i = blockIdx.x, lane = threadIdx.x;  // 64
    const int lab = label[i];
    const float4* pf = (const float4*)feat + (size_t)i * 128 + lane * 2;
    const float4* pw = (const float4*)wgt + (size_t)lab * 128 + lane * 2;
    float4 a = pf[0], b = pf[1], c = pw[0], d = pw[1];
    float s = a.x*c.x + a.y*c.y + a.z*c.z + a.w*c.w
            + b.x*d.x + b.y*d.y + b.z*d.z + b.w*d.w;
    for (int dd = 32; dd; dd >>= 1) s += __shfl_xor(s, dd, 64);
    if (lane == 0) cosgt[i] = s / (fnorm[i] * wnorm[lab]);
}

// ---------------- theta stats + per-row marginal gt logit value ----------------
__global__ void k_stats(const float* __restrict__ cosgt, float* __restrict__ gtml) {
    const int t = threadIdx.x;           // 1024
    const int lane = t & 63, w = t >> 6; // 16 waves
    __shared__ float smax[16], smin[16];
    __shared__ double ssum[16];
    __shared__ float bcast[3];
    float c0 = fminf(fmaxf(cosgt[t], -1.f), 1.f);
    float c1 = fminf(fmaxf(cosgt[t + 1024], -1.f), 1.f);
    float th0 = acosf(c0) * (180.f / PI_F);
    float th1 = acosf(c1) * (180.f / PI_F);
    float mx = fmaxf(th0, th1), mn = fminf(th0, th1);
    double sm = (double)th0 + (double)th1;
    for (int d = 32; d; d >>= 1) {
        mx = fmaxf(mx, __shfl_xor(mx, d, 64));
        mn = fminf(mn, __shfl_xor(mn, d, 64));
        sm += __shfl_xor(sm, d, 64);
    }
    if (lane == 0) { smax[w] = mx; smin[w] = mn; ssum[w] = sm; }
    __syncthreads();
    if (t == 0) {
        float MX = smax[0], MN = smin[0]; double SM = ssum[0];
        for (int j = 1; j < 16; ++j) {
            MX = fmaxf(MX, smax[j]); MN = fminf(MN, smin[j]); SM += ssum[j];
        }
        float avg = (float)(SM / 2048.0);
        float mhi = (MX < 90.f) ? (90.f - avg) * (PI_F / 180.f) : 0.f;
        float mlo = MN * (PI_F / 180.f);
        bcast[0] = avg; bcast[1] = mhi; bcast[2] = mlo;
    }
    __syncthreads();
    const float avg = bcast[0], mhi = bcast[1], mlo = bcast[2];
    #pragma unroll
    for (int k = 0; k < 2; ++k) {
        const int r = t + k * 1024;
        const float th = k ? th1 : th0;
        const float cg = k ? c1 : c0;
        const float m = (th > avg) ? mhi : mlo;
        const bool inside = cg > -cosf(m);
        const float add = inside ? m : 0.f;
        const float ext = inside ? 0.f : (-m * sinf(m));
        gtml[r] = SCALE_F * (cosf(acosf(cg) + add) + ext);
    }
}

// ---------------- main bf16 MFMA GEMM, 8 waves/block (reg bucket <=128 -> 16 waves/CU) ----
// 128x128 tile, BK=32, wave grid 2x4 (per-wave 64x32 => acc 8 x f32x4 = 32 AGPR).
// Double-buffered LDS via global_load_lds; bijective XCD swizzle for B-tile L2 reuse.
__global__ void __launch_bounds__(512, 4)
k_gemm(const u16* __restrict__ nfb, const u16* __restrict__ nwb,
       const int* __restrict__ label, const float* __restrict__ gtml,
       float* __restrict__ cosO, float* __restrict__ mlO,
       float* __restrict__ partial, float* __restrict__ cosLast) {
    __shared__ __align__(16) u16 lsA[2][4096];  // 8KB per buffer
    __shared__ __align__(16) u16 lsB[2][4096];
    const int tid = threadIdx.x;          // 0..511
    const int lane = tid & 63;
    const int wid = tid >> 6;             // 0..7
    const int wm = wid >> 2, wn = wid & 3;

    // bijective XCD swizzle (1328 = 8*166)
    const int lin = blockIdx.x;
    const int wg = (lin & 7) * (NWG / 8) + (lin >> 3);
    const int bx = wg >> 4;               // 0..82
    const int by = wg & 15;               // 0..15
    const int tm = by * 128;
    const int tn = bx * 128;

    f32x4 acc[4][2] = {};

    auto stage = [&](int buf, int kt) {
        const int kg2 = tid >> 7, row = tid & 127;     // slot = tid
        const u16* gA = nfb + ((size_t)(tm + row) * K_DIM + kt * 32 + kg2 * 8);
        const u16* gB = nwb + ((size_t)(tn + row) * K_DIM + kt * 32 + kg2 * 8);
        u16* lA = &lsA[buf][(size_t)(wid * 64) * 8];   // wave-uniform base; +lane*16B implicit
        u16* lB = &lsB[buf][(size_t)(wid * 64) * 8];
        __builtin_amdgcn_global_load_lds(
            (const __attribute__((address_space(1))) void*)gA,
            (__attribute__((address_space(3))) void*)lA, 16, 0, 0);
        __builtin_amdgcn_global_load_lds(
            (const __attribute__((address_space(1))) void*)gB,
            (__attribute__((address_space(3))) void*)lB, 16, 0, 0);
    };

    stage(0, 0);
    __syncthreads();
    const int kg = lane >> 4, lr = lane & 15;
    for (int kt = 0; kt < 16; ++kt) {
        const int cur = kt & 1;
        if (kt < 15) stage(cur ^ 1, kt + 1);
        short8v af[4], bfv[2];
        #pragma unroll
        for (int mf = 0; mf < 4; ++mf)
            af[mf] = *(const short8v*)&lsA[cur][(kg * 128 + wm * 64 + mf * 16 + lr) * 8];
        #pragma unroll
        for (int nf = 0; nf < 2; ++nf)
            bfv[nf] = *(const short8v*)&lsB[cur][(kg * 128 + wn * 32 + nf * 16 + lr) * 8];
        #pragma unroll
        for (int mf = 0; mf < 4; ++mf)
            #pragma unroll
            for (int nf = 0; nf < 2; ++nf)
                acc[mf][nf] = __builtin_amdgcn_mfma_f32_16x16x32_bf16(
                    af[mf], bfv[nf], acc[mf][nf], 0, 0, 0);
        __syncthreads();
    }

    // epilogue: cos, marginal logits (gt patched inline), exp partial row-sums, cos[:,label_last]
    const int labL = label[M_ROWS - 1];
    float* prow = partial + (size_t)(bx * 4 + wn) * M_ROWS;
    #pragma unroll
    for (int mf = 0; mf < 4; ++mf) {
        #pragma unroll
        for (int r = 0; r < 4; ++r) {
            const int row = tm + wm * 64 + mf * 16 + kg * 4 + r;
            const int lab = label[row];
            const float gml = gtml[row];
            float rs = 0.f;
            #pragma unroll
            for (int nf = 0; nf < 2; ++nf) {
                const int col = tn + wn * 32 + nf * 16 + lr;
                const float v = acc[mf][nf][r];
                if (col < N_COLS) {
                    const size_t idx = (size_t)row * N_COLS + col;
                    cosO[idx] = v;
                    mlO[idx] = (col == lab) ? gml : SCALE_F * v;
                    rs += __expf(SCALE_F * v);
                    if (col == labL) cosLast[row] = v;
                }
            }
            #pragma unroll
            for (int d = 1; d < 16; d <<= 1) rs += __shfl_xor(rs, d, 64);
            if (lr == 0) prow[row] = rs;
        }
    }
}

// ---------------- reduce partial row sums ----------------
__global__ void k_rowsum(const float* __restrict__ partial, float* __restrict__ rowsum) {
    const int row = blockIdx.x * 256 + threadIdx.x;  // 8 blocks x 256
    float s = 0.f;
    for (int j = 0; j < NSLOT; ++j) s += partial[(size_t)j * M_ROWS + row];
    rowsum[row] = s;
}

// ---------------- final scalar stats ----------------
__global__ void k_final(const float* __restrict__ rowsum, const float* __restrict__ cosLast,
                        float* __restrict__ outS) {
    const int t = threadIdx.x;           // 1024
    const int lane = t & 63, w = t >> 6;
    __shared__ float smin[16], smax[16];
    __shared__ double ssum[16], sbs[16];
    double psum = 0.0, bsum = 0.0;
    float mn = 1e30f, mx = -1e30f;
    #pragma unroll
    for (int k = 0; k < 2; ++k) {
        const int r = t + k * 1024;
        const float e = expf(SCALE_F * cosLast[r]);
        const float rsv = rowsum[r];
        const float p = e / rsv;
        psum += (double)p;
        bsum += (double)rsv - (double)e;
        mn = fminf(mn, p); mx = fmaxf(mx, p);
    }
    for (int d = 32; d; d >>= 1) {
        mn = fminf(mn, __shfl_xor(mn, d, 64));
        mx = fmaxf(mx, __shfl_xor(mx, d, 64));
        psum += __shfl_xor(psum, d, 64);
        bsum += __shfl_xor(bsum, d, 64);
    }
    if (lane == 0) { smin[w] = mn; smax[w] = mx; ssum[w] = psum; sbs[w] = bsum; }
    __syncthreads();
    if (t == 0) {
        float MN = smin[0], MX = smax[0]; double PS = ssum[0], BS = sbs[0];
        for (int j = 1; j < 16; ++j) {
            MN = fminf(MN, smin[j]); MX = fmaxf(MX, smax[j]);
            PS += ssum[j]; BS += sbs[j];
        }
        outS[0] = (float)(PS / 2048.0);                 // avg_p
        outS[1] = MN;                                   // min_p
        outS[2] = MX;                                   // max_p
        const double mb = BS / 2048.0 / (double)(N_COLS - 1);
        outS[3] = (float)(acos(log(mb) / 30.0) * (180.0 / 3.14159265358979));  // B_avg
    }
}

extern "C" void kernel_launch(void* const* d_in, const int* in_sizes, int n_in,
                              void* d_out, int out_size, void* d_ws, size_t ws_size,
                              hipStream_t stream) {
    const float* feat = (const float*)d_in[0];
    const int* label = (const int*)d_in[1];
    const float* weights = (const float*)d_in[2];

    char* ws = (char*)d_ws;
    u16* nfb      = (u16*)(ws);                       // 2,097,152 B
    u16* nwb      = (u16*)(ws + 2097152);             // 10,878,976 B -> 12,976,128
    float* fnorm  = (float*)(ws + 12976128);          // 8192 -> 12,984,320
    float* wnorm  = (float*)(ws + 12984320);          // 42,496 -> 13,026,816
    float* cosgt  = (float*)(ws + 13026816);          // 8192 -> 13,035,008
    float* gtml   = (float*)(ws + 13035008);          // 8192 -> 13,043,200
    float* rowsum = (float*)(ws + 13043200);          // 8192 -> 13,051,392
    float* cosLast= (float*)(ws + 13051392);          // 8192 -> 13,059,584
    float* partial= (float*)(ws + 13059584);          // 332*2048*4 = 2,719,744

    float* cosO = (float*)d_out;
    float* mlO  = cosO + (size_t)M_ROWS * N_COLS;
    float* outS = cosO + (size_t)2 * M_ROWS * N_COLS;

    k_normalize2<<<M_ROWS + N_PAD, 64, 0, stream>>>(feat, weights, nfb, nwb, fnorm, wnorm);
    k_gt_dot<<<M_ROWS, 64, 0, stream>>>(feat, weights, label, fnorm, wnorm, cosgt);
    k_stats<<<1, 1024, 0, stream>>>(cosgt, gtml);

    k_gemm<<<NWG, 512, 0, stream>>>(nfb, nwb, label, gtml, cosO, mlO, partial, cosLast);

    k_rowsum<<<8, 256, 0, stream>>>(partial, rowsum);
    k_final<<<1, 1024, 0, stream>>>(rowsum, cosLast, outS);
}